// Round 1
// baseline (248.899 us; speedup 1.0000x reference)
//
#include <hip/hip_runtime.h>

// MPNN layer: edge MLP (bf16 MFMA) -> CSR scatter-sum -> LN -> node MLP -> LN
// N=10000 nodes, E=160000 edges, H=128, NIN=128, DD=256 (sizes derived at runtime)

typedef __attribute__((ext_vector_type(8))) short bf16x8;
typedef __attribute__((ext_vector_type(4))) float f32x4;

__device__ __forceinline__ unsigned short f2bf(float f) {
  union { float f; unsigned u; } v; v.f = f;
  return (unsigned short)((v.u + 0x7fffu + ((v.u >> 16) & 1u)) >> 16);
}
__device__ __forceinline__ float bf2f(unsigned s) {
  union { unsigned u; float f; } v; v.u = s << 16;
  return v.f;
}
__device__ __forceinline__ float gelu_f(float x) {
  return 0.5f * x * (1.0f + erff(x * 0.70710678118654752f));
}

// ---------------- weight packing into MFMA B-fragment order ----------------
// b_frag[j] = B[k = ks*32 + (lane>>4)*8 + j][n = w*WC + ct*16 + (lane&15)]
// group g = w*(CT*KS) + ct*KS + ks ; dst[(g*64+lane)*8 + j]
__global__ void k_pack(const float* __restrict__ mw0, const float* __restrict__ mw1,
                       const float* __restrict__ dw0, const float* __restrict__ dw1,
                       const float* __restrict__ dw2,
                       unsigned short* __restrict__ pw0, unsigned short* __restrict__ pw1,
                       unsigned short* __restrict__ pd0, unsigned short* __restrict__ pd1,
                       unsigned short* __restrict__ pd2) {
  int g = blockIdx.x, lane = threadIdx.x;
  const float* src; unsigned short* dst; int K, N, WC, base;
  if (g < 64)       { src = mw0; dst = pw0; K = 256; N = 128; WC = 32; base = 0; }
  else if (g < 96)  { src = mw1; dst = pw1; K = 128; N = 128; WC = 32; base = 64; }
  else if (g < 160) { src = dw0; dst = pd0; K = 128; N = 256; WC = 64; base = 96; }
  else if (g < 288) { src = dw1; dst = pd1; K = 256; N = 256; WC = 32; base = 160; }
  else              { src = dw2; dst = pd2; K = 256; N = 128; WC = 32; base = 288; }
  int lg = g - base;
  int KS = K >> 5, CTKS = (WC >> 4) * KS;
  int w = lg / CTKS, rem = lg % CTKS, ct = rem / KS, ks = rem % KS;
  int col = w * WC + ct * 16 + (lane & 15);
  int k0 = ks * 32 + (lane >> 4) * 8;
  unsigned short o[8];
#pragma unroll
  for (int j = 0; j < 8; ++j) o[j] = f2bf(src[(size_t)(k0 + j) * N + col]);
  uint4 u;
  u.x = (unsigned)o[0] | ((unsigned)o[1] << 16);
  u.y = (unsigned)o[2] | ((unsigned)o[3] << 16);
  u.z = (unsigned)o[4] | ((unsigned)o[5] << 16);
  u.w = (unsigned)o[6] | ((unsigned)o[7] << 16);
  *(uint4*)(dst + (size_t)(lg * 64 + lane) * 8) = u;
}

// ---------------- CSR build ----------------
__global__ void k_hist(const int* __restrict__ eidx, int* __restrict__ counts, int E) {
  int e = blockIdx.x * 256 + threadIdx.x;
  if (e < E) atomicAdd(&counts[eidx[e]], 1);
}

__global__ __launch_bounds__(256) void k_scan(const int* __restrict__ counts,
                                              int* __restrict__ row_start,
                                              int* __restrict__ cursor, int Nn) {
  __shared__ int sm[256];
  int t = threadIdx.x;
  int chunk = (Nn + 255) / 256;
  int lo = t * chunk, hi = lo + chunk;
  if (hi > Nn) hi = Nn;
  int s = 0;
  for (int i = lo; i < hi; ++i) s += counts[i];
  sm[t] = s;
  __syncthreads();
  for (int o = 1; o < 256; o <<= 1) {
    int u = (t >= o) ? sm[t - o] : 0;
    __syncthreads();
    sm[t] += u;
    __syncthreads();
  }
  int run = sm[t] - s;  // exclusive prefix
  for (int i = lo; i < hi; ++i) {
    row_start[i] = run; cursor[i] = run; run += counts[i];
  }
  if (t == 255) row_start[Nn] = sm[255];
}

__global__ void k_scatter(const int* __restrict__ eidx, int* __restrict__ cursor,
                          int* __restrict__ eorder, int E) {
  int e = blockIdx.x * 256 + threadIdx.x;
  if (e < E) {
    int pos = atomicAdd(&cursor[eidx[e]], 1);
    eorder[pos] = e;
  }
}

// ---------------- fused edge MLP: h_msg = gelu(gelu(hE@W0+b0)@W1+b1) ----------------
// 4 waves, block tile 64 rows x 128 cols; wave owns 32 cols; weights in VGPRs.
__global__ __launch_bounds__(256, 2) void k_edge(
    const float* __restrict__ hE, const unsigned short* __restrict__ pw0,
    const unsigned short* __restrict__ pw1, const float* __restrict__ b0,
    const float* __restrict__ b1, unsigned short* __restrict__ hmsg, int E) {
  __shared__ __align__(16) char ldsA[64 * 512];  // bf16 [64][256], XOR-swizzled
  __shared__ __align__(16) char ldsH[64 * 256];  // bf16 [64][128], XOR-swizzled
  const int tid = threadIdx.x;
  const int wid = tid >> 6, lane = tid & 63;
  const int l15 = lane & 15, lhi = lane >> 4;
  const int wcol = wid * 32;

  bf16x8 B0[16], B1[8];
  {
    const uint4* p0 = (const uint4*)pw0 + (size_t)(wid * 16) * 64 + lane;
#pragma unroll
    for (int f = 0; f < 16; ++f) { uint4 v = p0[(size_t)f * 64]; B0[f] = *(bf16x8*)&v; }
    const uint4* p1 = (const uint4*)pw1 + (size_t)(wid * 8) * 64 + lane;
#pragma unroll
    for (int f = 0; f < 8; ++f) { uint4 v = p1[(size_t)f * 64]; B1[f] = *(bf16x8*)&v; }
  }
  float bb0[2], bb1[2];
#pragma unroll
  for (int ct = 0; ct < 2; ++ct) {
    bb0[ct] = b0[wcol + ct * 16 + l15];
    bb1[ct] = b1[wcol + ct * 16 + l15];
  }

  const int tiles = (E + 63) >> 6;
  for (int t = blockIdx.x; t < tiles; t += gridDim.x) {
    const int row0 = t << 6;
    const float4* src = (const float4*)hE + (size_t)row0 * 64;
    // stage 64x256 fp32 -> bf16 LDS (coalesced float4 loads)
#pragma unroll
    for (int p = 0; p < 16; ++p) {
      int idx = p * 256 + tid;
      int r = idx >> 6, c4 = idx & 63;
      float4 v = make_float4(0.f, 0.f, 0.f, 0.f);
      if (row0 + r < E) v = src[(size_t)r * 64 + c4];
      uint2 u;
      u.x = (unsigned)f2bf(v.x) | ((unsigned)f2bf(v.y) << 16);
      u.y = (unsigned)f2bf(v.z) | ((unsigned)f2bf(v.w) << 16);
      *(uint2*)(ldsA + r * 512 + ((c4 * 8) ^ ((r & 7) << 4))) = u;
    }
    __syncthreads();

    // GEMM1: K=256
    f32x4 acc[4][2];
#pragma unroll
    for (int mt = 0; mt < 4; ++mt)
#pragma unroll
      for (int ct = 0; ct < 2; ++ct) acc[mt][ct] = 0.f;
#pragma unroll
    for (int ks = 0; ks < 8; ++ks) {
      bf16x8 a[4];
#pragma unroll
      for (int mt = 0; mt < 4; ++mt) {
        int row = mt * 16 + l15;
        a[mt] = *(bf16x8*)(ldsA + row * 512 + ((ks * 64 + lhi * 16) ^ ((row & 7) << 4)));
      }
#pragma unroll
      for (int mt = 0; mt < 4; ++mt)
#pragma unroll
        for (int ct = 0; ct < 2; ++ct)
          acc[mt][ct] = __builtin_amdgcn_mfma_f32_16x16x32_bf16(a[mt], B0[ct * 8 + ks],
                                                               acc[mt][ct], 0, 0, 0);
    }
    // gelu + bias -> intermediate LDS (bf16)
#pragma unroll
    for (int mt = 0; mt < 4; ++mt)
#pragma unroll
      for (int ct = 0; ct < 2; ++ct)
#pragma unroll
        for (int j = 0; j < 4; ++j) {
          int r = mt * 16 + lhi * 4 + j;
          int col = wcol + ct * 16 + l15;
          float g = gelu_f(acc[mt][ct][j] + bb0[ct]);
          *(unsigned short*)(ldsH + r * 256 + ((col * 2) ^ ((r & 7) << 4))) = f2bf(g);
        }
    __syncthreads();

    // GEMM2: K=128
    f32x4 acc2[4][2];
#pragma unroll
    for (int mt = 0; mt < 4; ++mt)
#pragma unroll
      for (int ct = 0; ct < 2; ++ct) acc2[mt][ct] = 0.f;
#pragma unroll
    for (int ks = 0; ks < 4; ++ks) {
      bf16x8 a[4];
#pragma unroll
      for (int mt = 0; mt < 4; ++mt) {
        int row = mt * 16 + l15;
        a[mt] = *(bf16x8*)(ldsH + row * 256 + ((ks * 64 + lhi * 16) ^ ((row & 7) << 4)));
      }
#pragma unroll
      for (int mt = 0; mt < 4; ++mt)
#pragma unroll
        for (int ct = 0; ct < 2; ++ct)
          acc2[mt][ct] = __builtin_amdgcn_mfma_f32_16x16x32_bf16(a[mt], B1[ct * 4 + ks],
                                                                acc2[mt][ct], 0, 0, 0);
    }
    // gelu + bias -> global h_msg (bf16)
#pragma unroll
    for (int mt = 0; mt < 4; ++mt)
#pragma unroll
      for (int ct = 0; ct < 2; ++ct)
#pragma unroll
        for (int j = 0; j < 4; ++j) {
          int r = mt * 16 + lhi * 4 + j;
          if (row0 + r < E) {
            int col = wcol + ct * 16 + l15;
            hmsg[(size_t)(row0 + r) * 128 + col] = f2bf(gelu_f(acc2[mt][ct][j] + bb1[ct]));
          }
        }
  }
}

// ---------------- aggregate (CSR gather) + LN1, wave per node ----------------
__global__ __launch_bounds__(256) void k_aggln(
    const unsigned* __restrict__ hmsg, const float2* __restrict__ hV,
    const int* __restrict__ row_start, const int* __restrict__ eorder,
    const float* __restrict__ g1, const float* __restrict__ be1,
    float2* __restrict__ hv1f, unsigned* __restrict__ hv1b, int Nn) {
  int wid = threadIdx.x >> 6, lane = threadIdx.x & 63;
  int node = blockIdx.x * 4 + wid;
  if (node >= Nn) return;
  int s = row_start[node], e = row_start[node + 1];
  float s0 = 0.f, s1 = 0.f;
  int i = s;
  for (; i + 3 < e; i += 4) {
    int e0 = eorder[i], e1 = eorder[i + 1], e2 = eorder[i + 2], e3 = eorder[i + 3];
    unsigned v0 = hmsg[(size_t)e0 * 64 + lane];
    unsigned v1 = hmsg[(size_t)e1 * 64 + lane];
    unsigned v2 = hmsg[(size_t)e2 * 64 + lane];
    unsigned v3 = hmsg[(size_t)e3 * 64 + lane];
    s0 += bf2f(v0 & 0xffffu) + bf2f(v1 & 0xffffu) + bf2f(v2 & 0xffffu) + bf2f(v3 & 0xffffu);
    s1 += bf2f(v0 >> 16) + bf2f(v1 >> 16) + bf2f(v2 >> 16) + bf2f(v3 >> 16);
  }
  for (; i < e; ++i) {
    unsigned v = hmsg[(size_t)eorder[i] * 64 + lane];
    s0 += bf2f(v & 0xffffu);
    s1 += bf2f(v >> 16);
  }
  float2 hv = hV[(size_t)node * 64 + lane];
  float x0 = hv.x + s0 * (1.f / 30.f);
  float x1 = hv.y + s1 * (1.f / 30.f);
  float sum = x0 + x1, sq = x0 * x0 + x1 * x1;
#pragma unroll
  for (int off = 32; off > 0; off >>= 1) {
    sum += __shfl_xor(sum, off);
    sq += __shfl_xor(sq, off);
  }
  float mu = sum * (1.f / 128.f);
  float var = sq * (1.f / 128.f) - mu * mu;
  float rs = rsqrtf(var + 1e-5f);
  int c = lane * 2;
  float y0 = (x0 - mu) * rs * g1[c] + be1[c];
  float y1 = (x1 - mu) * rs * g1[c + 1] + be1[c + 1];
  hv1f[(size_t)node * 64 + lane] = make_float2(y0, y1);
  hv1b[(size_t)node * 64 + lane] = (unsigned)f2bf(y0) | ((unsigned)f2bf(y1) << 16);
}

// ---------------- dense MLP stage 0: d0 = gelu(x @ W0 + b0), K=128, N=256 ----------------
__global__ __launch_bounds__(256) void k_d0(const unsigned short* __restrict__ xb,
                                            const unsigned short* __restrict__ pd0,
                                            const float* __restrict__ bias,
                                            unsigned short* __restrict__ out, int Nn) {
  __shared__ __align__(16) char ldsA[64 * 256];
  const int tid = threadIdx.x, wid = tid >> 6, lane = tid & 63;
  const int l15 = lane & 15, lhi = lane >> 4;
  const int row0 = blockIdx.x * 64;
#pragma unroll
  for (int p = 0; p < 4; ++p) {
    int idx = p * 256 + tid;
    int r = idx >> 4, c = idx & 15;
    uint4 v = make_uint4(0u, 0u, 0u, 0u);
    if (row0 + r < Nn) v = ((const uint4*)xb)[(size_t)(row0 + r) * 16 + c];
    *(uint4*)(ldsA + r * 256 + ((c * 16) ^ ((r & 7) << 4))) = v;
  }
  bf16x8 B[16];
  {
    const uint4* p0 = (const uint4*)pd0 + (size_t)(wid * 16) * 64 + lane;
#pragma unroll
    for (int f = 0; f < 16; ++f) { uint4 v = p0[(size_t)f * 64]; B[f] = *(bf16x8*)&v; }
  }
  __syncthreads();
  f32x4 acc[4][4];
#pragma unroll
  for (int mt = 0; mt < 4; ++mt)
#pragma unroll
    for (int ct = 0; ct < 4; ++ct) acc[mt][ct] = 0.f;
#pragma unroll
  for (int ks = 0; ks < 4; ++ks) {
    bf16x8 a[4];
#pragma unroll
    for (int mt = 0; mt < 4; ++mt) {
      int row = mt * 16 + l15;
      a[mt] = *(bf16x8*)(ldsA + row * 256 + ((ks * 64 + lhi * 16) ^ ((row & 7) << 4)));
    }
#pragma unroll
    for (int mt = 0; mt < 4; ++mt)
#pragma unroll
      for (int ct = 0; ct < 4; ++ct)
        acc[mt][ct] = __builtin_amdgcn_mfma_f32_16x16x32_bf16(a[mt], B[ct * 4 + ks],
                                                             acc[mt][ct], 0, 0, 0);
  }
  float bb[4];
#pragma unroll
  for (int ct = 0; ct < 4; ++ct) bb[ct] = bias[wid * 64 + ct * 16 + l15];
#pragma unroll
  for (int mt = 0; mt < 4; ++mt)
#pragma unroll
    for (int ct = 0; ct < 4; ++ct)
#pragma unroll
      for (int j = 0; j < 4; ++j) {
        int r = row0 + mt * 16 + lhi * 4 + j;
        if (r < Nn) {
          int col = wid * 64 + ct * 16 + l15;
          out[(size_t)r * 256 + col] = f2bf(gelu_f(acc[mt][ct][j] + bb[ct]));
        }
      }
}

// ---------------- dense MLP stage 1: d1 = gelu(d0 @ W1 + b1), K=256, N=256, 8 waves ----------------
__global__ __launch_bounds__(512) void k_d1(const unsigned short* __restrict__ d0,
                                            const unsigned short* __restrict__ pd1,
                                            const float* __restrict__ bias,
                                            unsigned short* __restrict__ out, int Nn) {
  __shared__ __align__(16) char ldsA[64 * 512];
  const int tid = threadIdx.x, wid = tid >> 6, lane = tid & 63;
  const int l15 = lane & 15, lhi = lane >> 4;
  const int wcol = wid * 32;
  const int row0 = blockIdx.x * 64;
#pragma unroll
  for (int p = 0; p < 4; ++p) {
    int idx = p * 512 + tid;
    int r = idx >> 5, c = idx & 31;
    uint4 v = make_uint4(0u, 0u, 0u, 0u);
    if (row0 + r < Nn) v = ((const uint4*)d0)[(size_t)(row0 + r) * 32 + c];
    *(uint4*)(ldsA + r * 512 + ((c * 16) ^ ((r & 7) << 4))) = v;
  }
  bf16x8 B[16];
  {
    const uint4* p0 = (const uint4*)pd1 + (size_t)(wid * 16) * 64 + lane;
#pragma unroll
    for (int f = 0; f < 16; ++f) { uint4 v = p0[(size_t)f * 64]; B[f] = *(bf16x8*)&v; }
  }
  __syncthreads();
  f32x4 acc[4][2];
#pragma unroll
  for (int mt = 0; mt < 4; ++mt)
#pragma unroll
    for (int ct = 0; ct < 2; ++ct) acc[mt][ct] = 0.f;
#pragma unroll
  for (int ks = 0; ks < 8; ++ks) {
    bf16x8 a[4];
#pragma unroll
    for (int mt = 0; mt < 4; ++mt) {
      int row = mt * 16 + l15;
      a[mt] = *(bf16x8*)(ldsA + row * 512 + ((ks * 64 + lhi * 16) ^ ((row & 7) << 4)));
    }
#pragma unroll
    for (int mt = 0; mt < 4; ++mt)
#pragma unroll
      for (int ct = 0; ct < 2; ++ct)
        acc[mt][ct] = __builtin_amdgcn_mfma_f32_16x16x32_bf16(a[mt], B[ct * 8 + ks],
                                                             acc[mt][ct], 0, 0, 0);
  }
  float bb[2];
#pragma unroll
  for (int ct = 0; ct < 2; ++ct) bb[ct] = bias[wcol + ct * 16 + l15];
#pragma unroll
  for (int mt = 0; mt < 4; ++mt)
#pragma unroll
    for (int ct = 0; ct < 2; ++ct)
#pragma unroll
      for (int j = 0; j < 4; ++j) {
        int r = row0 + mt * 16 + lhi * 4 + j;
        if (r < Nn) {
          int col = wcol + ct * 16 + l15;
          out[(size_t)r * 256 + col] = f2bf(gelu_f(acc[mt][ct][j] + bb[ct]));
        }
      }
}

// ---------------- dense MLP stage 2 + residual + LN2 -> d_out, K=256, N=128 ----------------
__global__ __launch_bounds__(256) void k_d2(const unsigned short* __restrict__ d1,
                                            const unsigned short* __restrict__ pd2,
                                            const float* __restrict__ bias,
                                            const float* __restrict__ hv1f,
                                            const float* __restrict__ g2,
                                            const float* __restrict__ be2,
                                            float* __restrict__ out, int Nn) {
  __shared__ __align__(16) char ldsA[64 * 512];
  const int tid = threadIdx.x, wid = tid >> 6, lane = tid & 63;
  const int l15 = lane & 15, lhi = lane >> 4;
  const int wcol = wid * 32;
  const int row0 = blockIdx.x * 64;
#pragma unroll
  for (int p = 0; p < 8; ++p) {
    int idx = p * 256 + tid;
    int r = idx >> 5, c = idx & 31;
    uint4 v = make_uint4(0u, 0u, 0u, 0u);
    if (row0 + r < Nn) v = ((const uint4*)d1)[(size_t)(row0 + r) * 32 + c];
    *(uint4*)(ldsA + r * 512 + ((c * 16) ^ ((r & 7) << 4))) = v;
  }
  bf16x8 B[16];
  {
    const uint4* p0 = (const uint4*)pd2 + (size_t)(wid * 16) * 64 + lane;
#pragma unroll
    for (int f = 0; f < 16; ++f) { uint4 v = p0[(size_t)f * 64]; B[f] = *(bf16x8*)&v; }
  }
  __syncthreads();
  f32x4 acc[4][2];
#pragma unroll
  for (int mt = 0; mt < 4; ++mt)
#pragma unroll
    for (int ct = 0; ct < 2; ++ct) acc[mt][ct] = 0.f;
#pragma unroll
  for (int ks = 0; ks < 8; ++ks) {
    bf16x8 a[4];
#pragma unroll
    for (int mt = 0; mt < 4; ++mt) {
      int row = mt * 16 + l15;
      a[mt] = *(bf16x8*)(ldsA + row * 512 + ((ks * 64 + lhi * 16) ^ ((row & 7) << 4)));
    }
#pragma unroll
    for (int mt = 0; mt < 4; ++mt)
#pragma unroll
      for (int ct = 0; ct < 2; ++ct)
        acc[mt][ct] = __builtin_amdgcn_mfma_f32_16x16x32_bf16(a[mt], B[ct * 8 + ks],
                                                             acc[mt][ct], 0, 0, 0);
  }
  float bb[2];
#pragma unroll
  for (int ct = 0; ct < 2; ++ct) bb[ct] = bias[wcol + ct * 16 + l15];
  __syncthreads();  // done reading ldsA; reuse it as fp32 y[64][128]
  float* yl = (float*)ldsA;
#pragma unroll
  for (int mt = 0; mt < 4; ++mt)
#pragma unroll
    for (int ct = 0; ct < 2; ++ct)
#pragma unroll
      for (int j = 0; j < 4; ++j) {
        int r = mt * 16 + lhi * 4 + j;
        int grow = row0 + r;
        int col = wcol + ct * 16 + l15;
        float res = (grow < Nn) ? hv1f[(size_t)grow * 128 + col] : 0.f;
        yl[r * 128 + col] = acc[mt][ct][j] + bb[ct] + res;
      }
  __syncthreads();
  float g2a = g2[lane * 2], g2b = g2[lane * 2 + 1];
  float ba = be2[lane * 2], bbx = be2[lane * 2 + 1];
  for (int ii = 0; ii < 16; ++ii) {
    int r = wid * 16 + ii;
    int grow = row0 + r;
    if (grow >= Nn) continue;  // wave-uniform
    float2 xy = *(float2*)&yl[r * 128 + lane * 2];
    float sum = xy.x + xy.y, sq = xy.x * xy.x + xy.y * xy.y;
#pragma unroll
    for (int off = 32; off > 0; off >>= 1) {
      sum += __shfl_xor(sum, off);
      sq += __shfl_xor(sq, off);
    }
    float mu = sum * (1.f / 128.f);
    float var = sq * (1.f / 128.f) - mu * mu;
    float rs = rsqrtf(var + 1e-5f);
    float y0 = (xy.x - mu) * rs * g2a + ba;
    float y1 = (xy.y - mu) * rs * g2b + bbx;
    *(float2*)&out[(size_t)grow * 128 + lane * 2] = make_float2(y0, y1);
  }
}

// ---------------- host ----------------
extern "C" void kernel_launch(void* const* d_in, const int* in_sizes, int n_in,
                              void* d_out, int out_size, void* d_ws, size_t ws_size,
                              hipStream_t stream) {
  const float* hV  = (const float*)d_in[0];
  const float* hE  = (const float*)d_in[1];
  const int* eidx  = (const int*)d_in[2];
  const float* mw0 = (const float*)d_in[3];
  const float* mb0 = (const float*)d_in[4];
  const float* mw1 = (const float*)d_in[5];
  const float* mb1 = (const float*)d_in[6];
  const float* dw0 = (const float*)d_in[7];
  const float* db0 = (const float*)d_in[8];
  const float* dw1 = (const float*)d_in[9];
  const float* db1 = (const float*)d_in[10];
  const float* dw2 = (const float*)d_in[11];
  const float* db2 = (const float*)d_in[12];
  const float* g1  = (const float*)d_in[13];
  const float* be1 = (const float*)d_in[14];
  const float* g2  = (const float*)d_in[15];
  const float* be2 = (const float*)d_in[16];
  const int Nn = in_sizes[0] / 128;
  const int E  = in_sizes[1] / 256;

  char* ws = (char*)d_ws;
  size_t off = 0;
  auto alloc = [&](size_t bytes) -> char* {
    off = (off + 255) & ~(size_t)255;
    char* p = ws + off;
    off += bytes;
    return p;
  };
  unsigned short* hmsg = (unsigned short*)alloc((size_t)E * 128 * 2);
  float* hv1f          = (float*)alloc((size_t)Nn * 128 * 4);
  unsigned short* hv1b = (unsigned short*)alloc((size_t)Nn * 128 * 2);
  unsigned short* d0b  = (unsigned short*)alloc((size_t)Nn * 256 * 2);
  unsigned short* d1b  = (unsigned short*)alloc((size_t)Nn * 256 * 2);
  unsigned short* pw0  = (unsigned short*)alloc(32768 * 2);
  unsigned short* pw1  = (unsigned short*)alloc(16384 * 2);
  unsigned short* pd0  = (unsigned short*)alloc(32768 * 2);
  unsigned short* pd1  = (unsigned short*)alloc(65536 * 2);
  unsigned short* pd2  = (unsigned short*)alloc(32768 * 2);
  int* counts    = (int*)alloc((size_t)Nn * 4);
  int* row_start = (int*)alloc((size_t)(Nn + 1) * 4);
  int* cursor    = (int*)alloc((size_t)Nn * 4);
  int* eorder    = (int*)alloc((size_t)E * 4);

  hipMemsetAsync(counts, 0, (size_t)Nn * 4, stream);
  k_pack<<<352, 64, 0, stream>>>(mw0, mw1, dw0, dw1, dw2, pw0, pw1, pd0, pd1, pd2);
  k_hist<<<(E + 255) / 256, 256, 0, stream>>>(eidx, counts, E);
  k_scan<<<1, 256, 0, stream>>>(counts, row_start, cursor, Nn);
  k_scatter<<<(E + 255) / 256, 256, 0, stream>>>(eidx, cursor, eorder, E);
  k_edge<<<512, 256, 0, stream>>>(hE, pw0, pw1, mb0, mb1, hmsg, E);
  k_aggln<<<(Nn + 3) / 4, 256, 0, stream>>>((const unsigned*)hmsg, (const float2*)hV,
                                            row_start, eorder, g1, be1,
                                            (float2*)hv1f, (unsigned*)hv1b, Nn);
  const int nt = (Nn + 63) / 64;
  k_d0<<<nt, 256, 0, stream>>>(hv1b, pd0, db0, d0b, Nn);
  k_d1<<<nt, 512, 0, stream>>>(d0b, pd1, db1, d1b, Nn);
  k_d2<<<nt, 256, 0, stream>>>(d1b, pd2, db2, hv1f, g2, be2, (float*)d_out, Nn);
}

// Round 2
// 160.102 us; speedup vs baseline: 1.5546x; 1.5546x over previous
//
#include <hip/hip_runtime.h>
#include <hip/hip_bf16.h>

// MPNN layer: edge MLP (bf16 MFMA) -> CSR scatter-sum -> LN -> node MLP -> LN
// N=10000 nodes, E=160000 edges, H=128, NIN=128, DD=256 (sizes derived at runtime)

typedef __attribute__((ext_vector_type(8))) short bf16x8;
typedef __attribute__((ext_vector_type(4))) float f32x4;

__device__ __forceinline__ unsigned short f2bf(float f) {
  union { float f; unsigned u; } v; v.f = f;
  return (unsigned short)((v.u + 0x7fffu + ((v.u >> 16) & 1u)) >> 16);
}
__device__ __forceinline__ unsigned pk2bf(float a, float b) {
  __hip_bfloat162 h = __float22bfloat162_rn(make_float2(a, b));  // v_cvt_pk_bf16_f32
  union { __hip_bfloat162 h; unsigned u; } v; v.h = h;
  return v.u;
}
__device__ __forceinline__ float bf2f(unsigned s) {
  union { unsigned u; float f; } v; v.u = s << 16;
  return v.f;
}
// gelu via Abramowitz-Stegun 7.1.26 erf approx, |erf err| <= 1.5e-7
__device__ __forceinline__ float gelu_f(float x) {
  float u = x * 0.70710678118654752f;
  float au = fabsf(u);
  float t = __builtin_amdgcn_rcpf(1.0f + 0.3275911f * au);
  float poly = ((((1.061405429f * t - 1.453152027f) * t + 1.421413741f) * t -
                 0.284496736f) * t + 0.254829592f) * t;
  float e = __expf(-au * au);
  float erfu = copysignf(1.0f - poly * e, u);
  return 0.5f * x * (1.0f + erfu);
}

// ---------------- weight packing into MFMA B-fragment order ----------------
// b_frag[j] = B[k = ks*32 + (lane>>4)*8 + j][n = w*WC + ct*16 + (lane&15)]
// group g = w*(CT*KS) + ct*KS + ks ; dst[(g*64+lane)*8 + j]
__global__ void k_pack(const float* __restrict__ mw0, const float* __restrict__ mw1,
                       const float* __restrict__ dw0, const float* __restrict__ dw1,
                       const float* __restrict__ dw2,
                       unsigned short* __restrict__ pw0, unsigned short* __restrict__ pw1,
                       unsigned short* __restrict__ pd0, unsigned short* __restrict__ pd1,
                       unsigned short* __restrict__ pd2) {
  int g = blockIdx.x, lane = threadIdx.x;
  const float* src; unsigned short* dst; int K, N, WC, base;
  if (g < 64)       { src = mw0; dst = pw0; K = 256; N = 128; WC = 32; base = 0; }
  else if (g < 96)  { src = mw1; dst = pw1; K = 128; N = 128; WC = 32; base = 64; }
  else if (g < 160) { src = dw0; dst = pd0; K = 128; N = 256; WC = 64; base = 96; }
  else if (g < 288) { src = dw1; dst = pd1; K = 256; N = 256; WC = 32; base = 160; }
  else              { src = dw2; dst = pd2; K = 256; N = 128; WC = 32; base = 288; }
  int lg = g - base;
  int KS = K >> 5, CTKS = (WC >> 4) * KS;
  int w = lg / CTKS, rem = lg % CTKS, ct = rem / KS, ks = rem % KS;
  int col = w * WC + ct * 16 + (lane & 15);
  int k0 = ks * 32 + (lane >> 4) * 8;
  unsigned short o[8];
#pragma unroll
  for (int j = 0; j < 8; ++j) o[j] = f2bf(src[(size_t)(k0 + j) * N + col]);
  uint4 u;
  u.x = (unsigned)o[0] | ((unsigned)o[1] << 16);
  u.y = (unsigned)o[2] | ((unsigned)o[3] << 16);
  u.z = (unsigned)o[4] | ((unsigned)o[5] << 16);
  u.w = (unsigned)o[6] | ((unsigned)o[7] << 16);
  *(uint4*)(dst + (size_t)(lg * 64 + lane) * 8) = u;
}

// ---------------- CSR build ----------------
__global__ void k_hist(const int* __restrict__ eidx, int* __restrict__ counts, int E) {
  int e = blockIdx.x * 256 + threadIdx.x;
  if (e < E) atomicAdd(&counts[eidx[e]], 1);
}

__global__ __launch_bounds__(1024) void k_scan(const int* __restrict__ counts,
                                               int* __restrict__ row_start,
                                               int* __restrict__ cursor, int Nn) {
  __shared__ int sm[1024];
  int t = threadIdx.x;
  int chunk = (Nn + 1023) / 1024;
  int lo = t * chunk, hi = lo + chunk;
  if (hi > Nn) hi = Nn;
  int s = 0;
  for (int i = lo; i < hi; ++i) s += counts[i];
  sm[t] = s;
  __syncthreads();
  for (int o = 1; o < 1024; o <<= 1) {
    int u = (t >= o) ? sm[t - o] : 0;
    __syncthreads();
    sm[t] += u;
    __syncthreads();
  }
  int run = sm[t] - s;  // exclusive prefix
  for (int i = lo; i < hi; ++i) {
    row_start[i] = run; cursor[i] = run; run += counts[i];
  }
  if (t == 1023) row_start[Nn] = sm[1023];
}

__global__ void k_scatter(const int* __restrict__ eidx, int* __restrict__ cursor,
                          int* __restrict__ eorder, int E) {
  int e = blockIdx.x * 256 + threadIdx.x;
  if (e < E) {
    int pos = atomicAdd(&cursor[eidx[e]], 1);
    eorder[pos] = e;
  }
}

// ---------------- fused edge MLP: h_msg = gelu(gelu(hE@W0+b0)@W1+b1) ----------------
// One 64-row tile per block; 4 waves, wave owns 32 cols; weights in VGPRs.
// LDS: A tile bf16 [64][256] (32KB); H intermediate overlaid on first 16KB.
__global__ __launch_bounds__(256, 3) void k_edge(
    const float* __restrict__ hE, const unsigned short* __restrict__ pw0,
    const unsigned short* __restrict__ pw1, const float* __restrict__ b0,
    const float* __restrict__ b1, unsigned short* __restrict__ hmsg, int E) {
  __shared__ __align__(16) char ldsA[64 * 512];  // bf16 [64][256], XOR-swizzled; H overlays
  const int tid = threadIdx.x;
  const int wid = tid >> 6, lane = tid & 63;
  const int l15 = lane & 15, lhi = lane >> 4;
  const int wcol = wid * 32;

  bf16x8 B0[16], B1[8];
  {
    const uint4* p0 = (const uint4*)pw0 + (size_t)(wid * 16) * 64 + lane;
#pragma unroll
    for (int f = 0; f < 16; ++f) { uint4 v = p0[(size_t)f * 64]; B0[f] = *(bf16x8*)&v; }
    const uint4* p1 = (const uint4*)pw1 + (size_t)(wid * 8) * 64 + lane;
#pragma unroll
    for (int f = 0; f < 8; ++f) { uint4 v = p1[(size_t)f * 64]; B1[f] = *(bf16x8*)&v; }
  }
  float bb0[2], bb1[2];
#pragma unroll
  for (int ct = 0; ct < 2; ++ct) {
    bb0[ct] = b0[wcol + ct * 16 + l15];
    bb1[ct] = b1[wcol + ct * 16 + l15];
  }

  const int row0 = blockIdx.x << 6;
  const float4* src = (const float4*)hE + (size_t)row0 * 64;
  // stage 64x256 fp32 -> bf16 LDS (coalesced float4 loads, cvt_pk packing)
#pragma unroll
  for (int p = 0; p < 16; ++p) {
    int idx = p * 256 + tid;
    int r = idx >> 6, c4 = idx & 63;
    float4 v = make_float4(0.f, 0.f, 0.f, 0.f);
    if (row0 + r < E) v = src[(size_t)r * 64 + c4];
    uint2 u;
    u.x = pk2bf(v.x, v.y);
    u.y = pk2bf(v.z, v.w);
    *(uint2*)(ldsA + r * 512 + ((c4 * 8) ^ ((r & 7) << 4))) = u;
  }
  __syncthreads();

  // GEMM1: K=256
  f32x4 acc[4][2];
#pragma unroll
  for (int mt = 0; mt < 4; ++mt)
#pragma unroll
    for (int ct = 0; ct < 2; ++ct) acc[mt][ct] = 0.f;
#pragma unroll
  for (int ks = 0; ks < 8; ++ks) {
    bf16x8 a[4];
#pragma unroll
    for (int mt = 0; mt < 4; ++mt) {
      int row = mt * 16 + l15;
      a[mt] = *(bf16x8*)(ldsA + row * 512 + ((ks * 64 + lhi * 16) ^ ((row & 7) << 4)));
    }
#pragma unroll
    for (int mt = 0; mt < 4; ++mt)
#pragma unroll
      for (int ct = 0; ct < 2; ++ct)
        acc[mt][ct] = __builtin_amdgcn_mfma_f32_16x16x32_bf16(a[mt], B0[ct * 8 + ks],
                                                             acc[mt][ct], 0, 0, 0);
  }
  __syncthreads();  // all waves done reading A; safe to overlay H

  // gelu + bias -> intermediate LDS (bf16, overlaid on ldsA)
#pragma unroll
  for (int mt = 0; mt < 4; ++mt)
#pragma unroll
    for (int ct = 0; ct < 2; ++ct)
#pragma unroll
      for (int j = 0; j < 4; ++j) {
        int r = mt * 16 + lhi * 4 + j;
        int col = wcol + ct * 16 + l15;
        float g = gelu_f(acc[mt][ct][j] + bb0[ct]);
        *(unsigned short*)(ldsA + r * 256 + ((col * 2) ^ ((r & 7) << 4))) = f2bf(g);
      }
  __syncthreads();

  // GEMM2: K=128
  f32x4 acc2[4][2];
#pragma unroll
  for (int mt = 0; mt < 4; ++mt)
#pragma unroll
    for (int ct = 0; ct < 2; ++ct) acc2[mt][ct] = 0.f;
#pragma unroll
  for (int ks = 0; ks < 4; ++ks) {
    bf16x8 a[4];
#pragma unroll
    for (int mt = 0; mt < 4; ++mt) {
      int row = mt * 16 + l15;
      a[mt] = *(bf16x8*)(ldsA + row * 256 + ((ks * 64 + lhi * 16) ^ ((row & 7) << 4)));
    }
#pragma unroll
    for (int mt = 0; mt < 4; ++mt)
#pragma unroll
      for (int ct = 0; ct < 2; ++ct)
        acc2[mt][ct] = __builtin_amdgcn_mfma_f32_16x16x32_bf16(a[mt], B1[ct * 4 + ks],
                                                              acc2[mt][ct], 0, 0, 0);
  }
  // gelu + bias -> global h_msg (bf16)
#pragma unroll
  for (int mt = 0; mt < 4; ++mt)
#pragma unroll
    for (int ct = 0; ct < 2; ++ct)
#pragma unroll
      for (int j = 0; j < 4; ++j) {
        int r = mt * 16 + lhi * 4 + j;
        if (row0 + r < E) {
          int col = wcol + ct * 16 + l15;
          hmsg[(size_t)(row0 + r) * 128 + col] = f2bf(gelu_f(acc2[mt][ct][j] + bb1[ct]));
        }
      }
}

// ---------------- aggregate (CSR gather) + LN1, wave per node ----------------
__global__ __launch_bounds__(256) void k_aggln(
    const unsigned* __restrict__ hmsg, const float2* __restrict__ hV,
    const int* __restrict__ row_start, const int* __restrict__ eorder,
    const float* __restrict__ g1, const float* __restrict__ be1,
    float2* __restrict__ hv1f, unsigned* __restrict__ hv1b, int Nn) {
  int wid = threadIdx.x >> 6, lane = threadIdx.x & 63;
  int node = blockIdx.x * 4 + wid;
  if (node >= Nn) return;
  int s = row_start[node], e = row_start[node + 1];
  float s0 = 0.f, s1 = 0.f;
  int i = s;
  for (; i + 3 < e; i += 4) {
    int e0 = eorder[i], e1 = eorder[i + 1], e2 = eorder[i + 2], e3 = eorder[i + 3];
    unsigned v0 = hmsg[(size_t)e0 * 64 + lane];
    unsigned v1 = hmsg[(size_t)e1 * 64 + lane];
    unsigned v2 = hmsg[(size_t)e2 * 64 + lane];
    unsigned v3 = hmsg[(size_t)e3 * 64 + lane];
    s0 += bf2f(v0 & 0xffffu) + bf2f(v1 & 0xffffu) + bf2f(v2 & 0xffffu) + bf2f(v3 & 0xffffu);
    s1 += bf2f(v0 >> 16) + bf2f(v1 >> 16) + bf2f(v2 >> 16) + bf2f(v3 >> 16);
  }
  for (; i < e; ++i) {
    unsigned v = hmsg[(size_t)eorder[i] * 64 + lane];
    s0 += bf2f(v & 0xffffu);
    s1 += bf2f(v >> 16);
  }
  float2 hv = hV[(size_t)node * 64 + lane];
  float x0 = hv.x + s0 * (1.f / 30.f);
  float x1 = hv.y + s1 * (1.f / 30.f);
  float sum = x0 + x1, sq = x0 * x0 + x1 * x1;
#pragma unroll
  for (int off = 32; off > 0; off >>= 1) {
    sum += __shfl_xor(sum, off);
    sq += __shfl_xor(sq, off);
  }
  float mu = sum * (1.f / 128.f);
  float var = sq * (1.f / 128.f) - mu * mu;
  float rs = rsqrtf(var + 1e-5f);
  int c = lane * 2;
  float y0 = (x0 - mu) * rs * g1[c] + be1[c];
  float y1 = (x1 - mu) * rs * g1[c + 1] + be1[c + 1];
  hv1f[(size_t)node * 64 + lane] = make_float2(y0, y1);
  hv1b[(size_t)node * 64 + lane] = (unsigned)f2bf(y0) | ((unsigned)f2bf(y1) << 16);
}

// ---------------- dense MLP stage 0: d0 = gelu(x @ W0 + b0), K=128, N=256 ----------------
__global__ __launch_bounds__(256) void k_d0(const unsigned short* __restrict__ xb,
                                            const unsigned short* __restrict__ pd0,
                                            const float* __restrict__ bias,
                                            unsigned short* __restrict__ out, int Nn) {
  __shared__ __align__(16) char ldsA[64 * 256];
  const int tid = threadIdx.x, wid = tid >> 6, lane = tid & 63;
  const int l15 = lane & 15, lhi = lane >> 4;
  const int row0 = blockIdx.x * 64;
#pragma unroll
  for (int p = 0; p < 4; ++p) {
    int idx = p * 256 + tid;
    int r = idx >> 4, c = idx & 15;
    uint4 v = make_uint4(0u, 0u, 0u, 0u);
    if (row0 + r < Nn) v = ((const uint4*)xb)[(size_t)(row0 + r) * 16 + c];
    *(uint4*)(ldsA + r * 256 + ((c * 16) ^ ((r & 7) << 4))) = v;
  }
  bf16x8 B[16];
  {
    const uint4* p0 = (const uint4*)pd0 + (size_t)(wid * 16) * 64 + lane;
#pragma unroll
    for (int f = 0; f < 16; ++f) { uint4 v = p0[(size_t)f * 64]; B[f] = *(bf16x8*)&v; }
  }
  __syncthreads();
  f32x4 acc[4][4];
#pragma unroll
  for (int mt = 0; mt < 4; ++mt)
#pragma unroll
    for (int ct = 0; ct < 4; ++ct) acc[mt][ct] = 0.f;
#pragma unroll
  for (int ks = 0; ks < 4; ++ks) {
    bf16x8 a[4];
#pragma unroll
    for (int mt = 0; mt < 4; ++mt) {
      int row = mt * 16 + l15;
      a[mt] = *(bf16x8*)(ldsA + row * 256 + ((ks * 64 + lhi * 16) ^ ((row & 7) << 4)));
    }
#pragma unroll
    for (int mt = 0; mt < 4; ++mt)
#pragma unroll
      for (int ct = 0; ct < 4; ++ct)
        acc[mt][ct] = __builtin_amdgcn_mfma_f32_16x16x32_bf16(a[mt], B[ct * 4 + ks],
                                                             acc[mt][ct], 0, 0, 0);
  }
  float bb[4];
#pragma unroll
  for (int ct = 0; ct < 4; ++ct) bb[ct] = bias[wid * 64 + ct * 16 + l15];
#pragma unroll
  for (int mt = 0; mt < 4; ++mt)
#pragma unroll
    for (int ct = 0; ct < 4; ++ct)
#pragma unroll
      for (int j = 0; j < 4; ++j) {
        int r = row0 + mt * 16 + lhi * 4 + j;
        if (r < Nn) {
          int col = wid * 64 + ct * 16 + l15;
          out[(size_t)r * 256 + col] = f2bf(gelu_f(acc[mt][ct][j] + bb[ct]));
        }
      }
}

// ---------------- dense MLP stage 1: d1 = gelu(d0 @ W1 + b1), K=256, N=256, 8 waves ----------------
__global__ __launch_bounds__(512) void k_d1(const unsigned short* __restrict__ d0,
                                            const unsigned short* __restrict__ pd1,
                                            const float* __restrict__ bias,
                                            unsigned short* __restrict__ out, int Nn) {
  __shared__ __align__(16) char ldsA[64 * 512];
  const int tid = threadIdx.x, wid = tid >> 6, lane = tid & 63;
  const int l15 = lane & 15, lhi = lane >> 4;
  const int wcol = wid * 32;
  const int row0 = blockIdx.x * 64;
#pragma unroll
  for (int p = 0; p < 4; ++p) {
    int idx = p * 512 + tid;
    int r = idx >> 5, c = idx & 31;
    uint4 v = make_uint4(0u, 0u, 0u, 0u);
    if (row0 + r < Nn) v = ((const uint4*)d0)[(size_t)(row0 + r) * 32 + c];
    *(uint4*)(ldsA + r * 512 + ((c * 16) ^ ((r & 7) << 4))) = v;
  }
  bf16x8 B[16];
  {
    const uint4* p0 = (const uint4*)pd1 + (size_t)(wid * 16) * 64 + lane;
#pragma unroll
    for (int f = 0; f < 16; ++f) { uint4 v = p0[(size_t)f * 64]; B[f] = *(bf16x8*)&v; }
  }
  __syncthreads();
  f32x4 acc[4][2];
#pragma unroll
  for (int mt = 0; mt < 4; ++mt)
#pragma unroll
    for (int ct = 0; ct < 2; ++ct) acc[mt][ct] = 0.f;
#pragma unroll
  for (int ks = 0; ks < 8; ++ks) {
    bf16x8 a[4];
#pragma unroll
    for (int mt = 0; mt < 4; ++mt) {
      int row = mt * 16 + l15;
      a[mt] = *(bf16x8*)(ldsA + row * 512 + ((ks * 64 + lhi * 16) ^ ((row & 7) << 4)));
    }
#pragma unroll
    for (int mt = 0; mt < 4; ++mt)
#pragma unroll
      for (int ct = 0; ct < 2; ++ct)
        acc[mt][ct] = __builtin_amdgcn_mfma_f32_16x16x32_bf16(a[mt], B[ct * 8 + ks],
                                                             acc[mt][ct], 0, 0, 0);
  }
  float bb[2];
#pragma unroll
  for (int ct = 0; ct < 2; ++ct) bb[ct] = bias[wcol + ct * 16 + l15];
#pragma unroll
  for (int mt = 0; mt < 4; ++mt)
#pragma unroll
    for (int ct = 0; ct < 2; ++ct)
#pragma unroll
      for (int j = 0; j < 4; ++j) {
        int r = row0 + mt * 16 + lhi * 4 + j;
        if (r < Nn) {
          int col = wcol + ct * 16 + l15;
          out[(size_t)r * 256 + col] = f2bf(gelu_f(acc[mt][ct][j] + bb[ct]));
        }
      }
}

// ---------------- dense MLP stage 2 + residual + LN2 -> d_out, K=256, N=128 ----------------
__global__ __launch_bounds__(256) void k_d2(const unsigned short* __restrict__ d1,
                                            const unsigned short* __restrict__ pd2,
                                            const float* __restrict__ bias,
                                            const float* __restrict__ hv1f,
                                            const float* __restrict__ g2,
                                            const float* __restrict__ be2,
                                            float* __restrict__ out, int Nn) {
  __shared__ __align__(16) char ldsA[64 * 512];
  const int tid = threadIdx.x, wid = tid >> 6, lane = tid & 63;
  const int l15 = lane & 15, lhi = lane >> 4;
  const int wcol = wid * 32;
  const int row0 = blockIdx.x * 64;
#pragma unroll
  for (int p = 0; p < 8; ++p) {
    int idx = p * 256 + tid;
    int r = idx >> 5, c = idx & 31;
    uint4 v = make_uint4(0u, 0u, 0u, 0u);
    if (row0 + r < Nn) v = ((const uint4*)d1)[(size_t)(row0 + r) * 32 + c];
    *(uint4*)(ldsA + r * 512 + ((c * 16) ^ ((r & 7) << 4))) = v;
  }
  bf16x8 B[16];
  {
    const uint4* p0 = (const uint4*)pd2 + (size_t)(wid * 16) * 64 + lane;
#pragma unroll
    for (int f = 0; f < 16; ++f) { uint4 v = p0[(size_t)f * 64]; B[f] = *(bf16x8*)&v; }
  }
  __syncthreads();
  f32x4 acc[4][2];
#pragma unroll
  for (int mt = 0; mt < 4; ++mt)
#pragma unroll
    for (int ct = 0; ct < 2; ++ct) acc[mt][ct] = 0.f;
#pragma unroll
  for (int ks = 0; ks < 8; ++ks) {
    bf16x8 a[4];
#pragma unroll
    for (int mt = 0; mt < 4; ++mt) {
      int row = mt * 16 + l15;
      a[mt] = *(bf16x8*)(ldsA + row * 512 + ((ks * 64 + lhi * 16) ^ ((row & 7) << 4)));
    }
#pragma unroll
    for (int mt = 0; mt < 4; ++mt)
#pragma unroll
      for (int ct = 0; ct < 2; ++ct)
        acc[mt][ct] = __builtin_amdgcn_mfma_f32_16x16x32_bf16(a[mt], B[ct * 8 + ks],
                                                             acc[mt][ct], 0, 0, 0);
  }
  float bb[2];
#pragma unroll
  for (int ct = 0; ct < 2; ++ct) bb[ct] = bias[wcol + ct * 16 + l15];
  __syncthreads();  // done reading ldsA; reuse it as fp32 y[64][128]
  float* yl = (float*)ldsA;
#pragma unroll
  for (int mt = 0; mt < 4; ++mt)
#pragma unroll
    for (int ct = 0; ct < 2; ++ct)
#pragma unroll
      for (int j = 0; j < 4; ++j) {
        int r = mt * 16 + lhi * 4 + j;
        int grow = row0 + r;
        int col = wcol + ct * 16 + l15;
        float res = (grow < Nn) ? hv1f[(size_t)grow * 128 + col] : 0.f;
        yl[r * 128 + col] = acc[mt][ct][j] + bb[ct] + res;
      }
  __syncthreads();
  float g2a = g2[lane * 2], g2b = g2[lane * 2 + 1];
  float ba = be2[lane * 2], bbx = be2[lane * 2 + 1];
  for (int ii = 0; ii < 16; ++ii) {
    int r = wid * 16 + ii;
    int grow = row0 + r;
    if (grow >= Nn) continue;  // wave-uniform
    float2 xy = *(float2*)&yl[r * 128 + lane * 2];
    float sum = xy.x + xy.y, sq = xy.x * xy.x + xy.y * xy.y;
#pragma unroll
    for (int off = 32; off > 0; off >>= 1) {
      sum += __shfl_xor(sum, off);
      sq += __shfl_xor(sq, off);
    }
    float mu = sum * (1.f / 128.f);
    float var = sq * (1.f / 128.f) - mu * mu;
    float rs = rsqrtf(var + 1e-5f);
    float y0 = (xy.x - mu) * rs * g2a + ba;
    float y1 = (xy.y - mu) * rs * g2b + bbx;
    *(float2*)&out[(size_t)grow * 128 + lane * 2] = make_float2(y0, y1);
  }
}

// ---------------- host ----------------
extern "C" void kernel_launch(void* const* d_in, const int* in_sizes, int n_in,
                              void* d_out, int out_size, void* d_ws, size_t ws_size,
                              hipStream_t stream) {
  const float* hV  = (const float*)d_in[0];
  const float* hE  = (const float*)d_in[1];
  const int* eidx  = (const int*)d_in[2];
  const float* mw0 = (const float*)d_in[3];
  const float* mb0 = (const float*)d_in[4];
  const float* mw1 = (const float*)d_in[5];
  const float* mb1 = (const float*)d_in[6];
  const float* dw0 = (const float*)d_in[7];
  const float* db0 = (const float*)d_in[8];
  const float* dw1 = (const float*)d_in[9];
  const float* db1 = (const float*)d_in[10];
  const float* dw2 = (const float*)d_in[11];
  const float* db2 = (const float*)d_in[12];
  const float* g1  = (const float*)d_in[13];
  const float* be1 = (const float*)d_in[14];
  const float* g2  = (const float*)d_in[15];
  const float* be2 = (const float*)d_in[16];
  const int Nn = in_sizes[0] / 128;
  const int E  = in_sizes[1] / 256;

  char* ws = (char*)d_ws;
  size_t off = 0;
  auto alloc = [&](size_t bytes) -> char* {
    off = (off + 255) & ~(size_t)255;
    char* p = ws + off;
    off += bytes;
    return p;
  };
  unsigned short* hmsg = (unsigned short*)alloc((size_t)E * 128 * 2);
  float* hv1f          = (float*)alloc((size_t)Nn * 128 * 4);
  unsigned short* hv1b = (unsigned short*)alloc((size_t)Nn * 128 * 2);
  unsigned short* d0b  = (unsigned short*)alloc((size_t)Nn * 256 * 2);
  unsigned short* d1b  = (unsigned short*)alloc((size_t)Nn * 256 * 2);
  unsigned short* pw0  = (unsigned short*)alloc(32768 * 2);
  unsigned short* pw1  = (unsigned short*)alloc(16384 * 2);
  unsigned short* pd0  = (unsigned short*)alloc(32768 * 2);
  unsigned short* pd1  = (unsigned short*)alloc(65536 * 2);
  unsigned short* pd2  = (unsigned short*)alloc(32768 * 2);
  int* counts    = (int*)alloc((size_t)Nn * 4);
  int* row_start = (int*)alloc((size_t)(Nn + 1) * 4);
  int* cursor    = (int*)alloc((size_t)Nn * 4);
  int* eorder    = (int*)alloc((size_t)E * 4);

  hipMemsetAsync(counts, 0, (size_t)Nn * 4, stream);
  k_pack<<<352, 64, 0, stream>>>(mw0, mw1, dw0, dw1, dw2, pw0, pw1, pd0, pd1, pd2);
  k_hist<<<(E + 255) / 256, 256, 0, stream>>>(eidx, counts, E);
  k_scan<<<1, 1024, 0, stream>>>(counts, row_start, cursor, Nn);
  k_scatter<<<(E + 255) / 256, 256, 0, stream>>>(eidx, cursor, eorder, E);
  const int etiles = (E + 63) / 64;
  k_edge<<<etiles, 256, 0, stream>>>(hE, pw0, pw1, mb0, mb1, hmsg, E);
  k_aggln<<<(Nn + 3) / 4, 256, 0, stream>>>((const unsigned*)hmsg, (const float2*)hV,
                                            row_start, eorder, g1, be1,
                                            (float2*)hv1f, (unsigned*)hv1b, Nn);
  const int nt = (Nn + 63) / 64;
  k_d0<<<nt, 256, 0, stream>>>(hv1b, pd0, db0, d0b, Nn);
  k_d1<<<nt, 512, 0, stream>>>(d0b, pd1, db1, d1b, Nn);
  k_d2<<<nt, 256, 0, stream>>>(d1b, pd2, db2, hv1f, g2, be2, (float*)d_out, Nn);
}

// Round 3
// 144.529 us; speedup vs baseline: 1.7221x; 1.1078x over previous
//
#include <hip/hip_runtime.h>
#include <hip/hip_bf16.h>

// MPNN layer: edge MLP (DMA-pipelined bf16 MFMA) -> CSR scatter-sum -> LN ->
// fused dense MLP (3 GEMMs) + LN2.  N=10000, E=160000, H=128, NIN=128, DD=256.

typedef __attribute__((ext_vector_type(8))) short bf16x8;
typedef __attribute__((ext_vector_type(4))) float f32x4;

__device__ __forceinline__ unsigned short f2bf(float f) {
  union { float f; unsigned u; } v; v.f = f;
  return (unsigned short)((v.u + 0x7fffu + ((v.u >> 16) & 1u)) >> 16);
}
__device__ __forceinline__ unsigned pk2bf(float a, float b) {
  __hip_bfloat162 h = __float22bfloat162_rn(make_float2(a, b));  // v_cvt_pk_bf16_f32
  union { __hip_bfloat162 h; unsigned u; } v; v.h = h;
  return v.u;
}
__device__ __forceinline__ float bf2f(unsigned s) {
  union { unsigned u; float f; } v; v.u = s << 16;
  return v.f;
}
// gelu via Abramowitz-Stegun 7.1.26 erf approx, |erf err| <= 1.5e-7
__device__ __forceinline__ float gelu_f(float x) {
  float u = x * 0.70710678118654752f;
  float au = fabsf(u);
  float t = __builtin_amdgcn_rcpf(1.0f + 0.3275911f * au);
  float poly = ((((1.061405429f * t - 1.453152027f) * t + 1.421413741f) * t -
                 0.284496736f) * t + 0.254829592f) * t;
  float e = __expf(-au * au);
  float erfu = copysignf(1.0f - poly * e, u);
  return 0.5f * x * (1.0f + erfu);
}

__device__ __forceinline__ void gl2lds16(const void* g, void* l) {
  __builtin_amdgcn_global_load_lds((const __attribute__((address_space(1))) unsigned*)g,
                                   (__attribute__((address_space(3))) unsigned*)l, 16, 0, 0);
}

// ---------------- weight packing into MFMA B-fragment order ----------------
// b_frag[j] = B[k = ks*32 + (lane>>4)*8 + j][n = w*WC + ct*16 + (lane&15)]
// group g = w*(CT*KS) + ct*KS + ks ; dst[(g*64+lane)*8 + j]
__global__ void k_pack(const float* __restrict__ mw0, const float* __restrict__ mw1,
                       const float* __restrict__ dw0, const float* __restrict__ dw1,
                       const float* __restrict__ dw2,
                       unsigned short* __restrict__ pw0, unsigned short* __restrict__ pw1,
                       unsigned short* __restrict__ pd0, unsigned short* __restrict__ pd1,
                       unsigned short* __restrict__ pd2) {
  int g = blockIdx.x, lane = threadIdx.x;
  const float* src; unsigned short* dst; int K, N, WC, base;
  if (g < 64)       { src = mw0; dst = pw0; K = 256; N = 128; WC = 32; base = 0; }
  else if (g < 96)  { src = mw1; dst = pw1; K = 128; N = 128; WC = 32; base = 64; }
  else if (g < 160) { src = dw0; dst = pd0; K = 128; N = 256; WC = 64; base = 96; }
  else if (g < 288) { src = dw1; dst = pd1; K = 256; N = 256; WC = 64; base = 160; }
  else              { src = dw2; dst = pd2; K = 256; N = 128; WC = 32; base = 288; }
  int lg = g - base;
  int KS = K >> 5, CTKS = (WC >> 4) * KS;
  int w = lg / CTKS, rem = lg % CTKS, ct = rem / KS, ks = rem % KS;
  int col = w * WC + ct * 16 + (lane & 15);
  int k0 = ks * 32 + (lane >> 4) * 8;
  unsigned short o[8];
#pragma unroll
  for (int j = 0; j < 8; ++j) o[j] = f2bf(src[(size_t)(k0 + j) * N + col]);
  uint4 u;
  u.x = (unsigned)o[0] | ((unsigned)o[1] << 16);
  u.y = (unsigned)o[2] | ((unsigned)o[3] << 16);
  u.z = (unsigned)o[4] | ((unsigned)o[5] << 16);
  u.w = (unsigned)o[6] | ((unsigned)o[7] << 16);
  *(uint4*)(dst + (size_t)(lg * 64 + lane) * 8) = u;
}

// ---------------- CSR build ----------------
__global__ void k_hist(const int* __restrict__ eidx, int* __restrict__ counts, int E) {
  int e = blockIdx.x * 256 + threadIdx.x;
  if (e < E) atomicAdd(&counts[eidx[e]], 1);
}

__global__ __launch_bounds__(1024) void k_scan(const int* __restrict__ counts,
                                               int* __restrict__ row_start,
                                               int* __restrict__ cursor, int Nn) {
  __shared__ int sm[1024];
  int t = threadIdx.x;
  int chunk = (Nn + 1023) / 1024;
  int lo = t * chunk, hi = lo + chunk;
  if (hi > Nn) hi = Nn;
  int s = 0;
  for (int i = lo; i < hi; ++i) s += counts[i];
  sm[t] = s;
  __syncthreads();
  for (int o = 1; o < 1024; o <<= 1) {
    int u = (t >= o) ? sm[t - o] : 0;
    __syncthreads();
    sm[t] += u;
    __syncthreads();
  }
  int run = sm[t] - s;  // exclusive prefix
  for (int i = lo; i < hi; ++i) {
    row_start[i] = run; cursor[i] = run; run += counts[i];
  }
  if (t == 1023) row_start[Nn] = sm[1023];
}

__global__ void k_scatter(const int* __restrict__ eidx, int* __restrict__ cursor,
                          int* __restrict__ eorder, int E) {
  int e = blockIdx.x * 256 + threadIdx.x;
  if (e < E) {
    int pos = atomicAdd(&cursor[eidx[e]], 1);
    eorder[pos] = e;
  }
}

// ---------------- fused edge MLP: h_msg = gelu(gelu(hE@W0+b0)@W1+b1) ----------------
// Persistent, 2 blocks/CU. 32-row tiles, fp32 A DMA'd to LDS (double-buffered,
// row stride 1040B for bank-conflict-free b128 reads), bf16 cvt on fragment read.
// Counted vmcnt(8) keeps next-tile DMA in flight across the barrier.
#define AST 1040
#define ABUF 33280
__global__ __launch_bounds__(256, 2) void k_edge(
    const float* __restrict__ hE, const unsigned short* __restrict__ pw0,
    const unsigned short* __restrict__ pw1, const float* __restrict__ b0,
    const float* __restrict__ b1, unsigned short* __restrict__ hmsg, int E) {
  __shared__ __align__(16) char lds[2 * ABUF + 8192];  // 2 fp32 A bufs + H bf16 [32][128] sw
  char* Hb = lds + 2 * ABUF;
  const int tid = threadIdx.x;
  const int wid = tid >> 6, lane = tid & 63;
  const int l15 = lane & 15, lhi = lane >> 4;
  const int wcol = wid * 32;

  bf16x8 B0[16], B1[8];
  {
    const uint4* p0 = (const uint4*)pw0 + (size_t)(wid * 16) * 64 + lane;
#pragma unroll
    for (int f = 0; f < 16; ++f) { uint4 v = p0[(size_t)f * 64]; B0[f] = *(bf16x8*)&v; }
    const uint4* p1 = (const uint4*)pw1 + (size_t)(wid * 8) * 64 + lane;
#pragma unroll
    for (int f = 0; f < 8; ++f) { uint4 v = p1[(size_t)f * 64]; B1[f] = *(bf16x8*)&v; }
  }
  float bb0[2], bb1[2];
#pragma unroll
  for (int ct = 0; ct < 2; ++ct) {
    bb0[ct] = b0[wcol + ct * 16 + l15];
    bb1[ct] = b1[wcol + ct * 16 + l15];
  }
  __syncthreads();  // drain all outstanding (weights) so vmcnt counting is exact

  const int TILES = (E + 31) >> 5;
  auto STAGE = [&](int tile, int buf) {
    char* dstb = lds + buf * ABUF + (wid * 8) * AST;
#pragma unroll
    for (int i = 0; i < 8; ++i) {
      int grow = tile * 32 + wid * 8 + i;
      grow = grow < E ? grow : E - 1;
      const float* g = hE + (size_t)grow * 256 + lane * 4;
      gl2lds16(g, dstb + i * AST);
    }
  };

  int t = blockIdx.x;
  int cur = 0;
  if (t < TILES) STAGE(t, 0);
  for (; t < TILES; t += gridDim.x) {
    int tn = t + gridDim.x;
    if (tn < TILES) {
      STAGE(tn, cur ^ 1);
      asm volatile("s_waitcnt vmcnt(8)" ::: "memory");
    } else {
      asm volatile("s_waitcnt vmcnt(0)" ::: "memory");
    }
    __builtin_amdgcn_s_barrier();
    __builtin_amdgcn_sched_barrier(0);

    // GEMM1: K=256, fp32 A in LDS -> cvt_pk to bf16 fragments
    const char* A = lds + cur * ABUF;
    f32x4 acc[2][2];
#pragma unroll
    for (int mt = 0; mt < 2; ++mt)
#pragma unroll
      for (int ct = 0; ct < 2; ++ct) acc[mt][ct] = 0.f;
#pragma unroll
    for (int ks = 0; ks < 8; ++ks) {
      bf16x8 a[2];
#pragma unroll
      for (int mt = 0; mt < 2; ++mt) {
        int row = mt * 16 + l15;
        const char* p = A + row * AST + ks * 128 + lhi * 32;
        f32x4 lo = *(const f32x4*)p;
        f32x4 hi = *(const f32x4*)(p + 16);
        union { unsigned u[4]; bf16x8 v; } pk;
        pk.u[0] = pk2bf(lo[0], lo[1]);
        pk.u[1] = pk2bf(lo[2], lo[3]);
        pk.u[2] = pk2bf(hi[0], hi[1]);
        pk.u[3] = pk2bf(hi[2], hi[3]);
        a[mt] = pk.v;
      }
#pragma unroll
      for (int mt = 0; mt < 2; ++mt)
#pragma unroll
        for (int ct = 0; ct < 2; ++ct)
          acc[mt][ct] = __builtin_amdgcn_mfma_f32_16x16x32_bf16(a[mt], B0[ct * 8 + ks],
                                                               acc[mt][ct], 0, 0, 0);
    }
    // gelu + bias -> H (bf16, swizzled)
#pragma unroll
    for (int mt = 0; mt < 2; ++mt)
#pragma unroll
      for (int ct = 0; ct < 2; ++ct)
#pragma unroll
        for (int j = 0; j < 4; ++j) {
          int r = mt * 16 + lhi * 4 + j;
          int col = wcol + ct * 16 + l15;
          float g = gelu_f(acc[mt][ct][j] + bb0[ct]);
          *(unsigned short*)(Hb + r * 256 + ((col * 2) ^ ((r & 7) << 4))) = f2bf(g);
        }
    asm volatile("s_waitcnt lgkmcnt(0)" ::: "memory");
    __builtin_amdgcn_s_barrier();
    __builtin_amdgcn_sched_barrier(0);

    // GEMM2: K=128 from H
    f32x4 acc2[2][2];
#pragma unroll
    for (int mt = 0; mt < 2; ++mt)
#pragma unroll
      for (int ct = 0; ct < 2; ++ct) acc2[mt][ct] = 0.f;
#pragma unroll
    for (int ks = 0; ks < 4; ++ks) {
      bf16x8 a[2];
#pragma unroll
      for (int mt = 0; mt < 2; ++mt) {
        int row = mt * 16 + l15;
        a[mt] = *(bf16x8*)(Hb + row * 256 + ((ks * 64 + lhi * 16) ^ ((row & 7) << 4)));
      }
#pragma unroll
      for (int mt = 0; mt < 2; ++mt)
#pragma unroll
        for (int ct = 0; ct < 2; ++ct)
          acc2[mt][ct] = __builtin_amdgcn_mfma_f32_16x16x32_bf16(a[mt], B1[ct * 4 + ks],
                                                                acc2[mt][ct], 0, 0, 0);
    }
    // gelu + bias -> global h_msg (bf16)
    const int row0 = t * 32;
#pragma unroll
    for (int mt = 0; mt < 2; ++mt)
#pragma unroll
      for (int ct = 0; ct < 2; ++ct)
#pragma unroll
        for (int j = 0; j < 4; ++j) {
          int r = row0 + mt * 16 + lhi * 4 + j;
          if (r < E) {
            int col = wcol + ct * 16 + l15;
            hmsg[(size_t)r * 128 + col] = f2bf(gelu_f(acc2[mt][ct][j] + bb1[ct]));
          }
        }
    cur ^= 1;
  }
}

// ---------------- aggregate (CSR gather) + LN1, wave per node ----------------
__global__ __launch_bounds__(256) void k_aggln(
    const unsigned* __restrict__ hmsg, const float2* __restrict__ hV,
    const int* __restrict__ row_start, const int* __restrict__ eorder,
    const float* __restrict__ g1, const float* __restrict__ be1,
    float2* __restrict__ hv1f, unsigned* __restrict__ hv1b, int Nn) {
  int wid = threadIdx.x >> 6, lane = threadIdx.x & 63;
  int node = blockIdx.x * 4 + wid;
  if (node >= Nn) return;
  int s = row_start[node], e = row_start[node + 1];
  float s0 = 0.f, s1 = 0.f;
  int i = s;
  for (; i + 3 < e; i += 4) {
    int e0 = eorder[i], e1 = eorder[i + 1], e2 = eorder[i + 2], e3 = eorder[i + 3];
    unsigned v0 = hmsg[(size_t)e0 * 64 + lane];
    unsigned v1 = hmsg[(size_t)e1 * 64 + lane];
    unsigned v2 = hmsg[(size_t)e2 * 64 + lane];
    unsigned v3 = hmsg[(size_t)e3 * 64 + lane];
    s0 += bf2f(v0 & 0xffffu) + bf2f(v1 & 0xffffu) + bf2f(v2 & 0xffffu) + bf2f(v3 & 0xffffu);
    s1 += bf2f(v0 >> 16) + bf2f(v1 >> 16) + bf2f(v2 >> 16) + bf2f(v3 >> 16);
  }
  for (; i < e; ++i) {
    unsigned v = hmsg[(size_t)eorder[i] * 64 + lane];
    s0 += bf2f(v & 0xffffu);
    s1 += bf2f(v >> 16);
  }
  float2 hv = hV[(size_t)node * 64 + lane];
  float x0 = hv.x + s0 * (1.f / 30.f);
  float x1 = hv.y + s1 * (1.f / 30.f);
  float sum = x0 + x1, sq = x0 * x0 + x1 * x1;
#pragma unroll
  for (int off = 32; off > 0; off >>= 1) {
    sum += __shfl_xor(sum, off);
    sq += __shfl_xor(sq, off);
  }
  float mu = sum * (1.f / 128.f);
  float var = sq * (1.f / 128.f) - mu * mu;
  float rs = rsqrtf(var + 1e-5f);
  int c = lane * 2;
  float y0 = (x0 - mu) * rs * g1[c] + be1[c];
  float y1 = (x1 - mu) * rs * g1[c + 1] + be1[c + 1];
  hv1f[(size_t)node * 64 + lane] = make_float2(y0, y1);
  hv1b[(size_t)node * 64 + lane] = (unsigned)f2bf(y0) | ((unsigned)f2bf(y1) << 16);
}

// ---------------- fused dense MLP: 3 GEMMs + residual + LN2, 64 rows/block ----------------
// LDS: A0 bf16[64][128]sw (16K) | D0 bf16[64][256]sw (32K, Y fp32 overlays) | D1 (32K)
__global__ __launch_bounds__(256, 1) void k_node(
    const unsigned short* __restrict__ xb, const unsigned short* __restrict__ pd0,
    const unsigned short* __restrict__ pd1, const unsigned short* __restrict__ pd2,
    const float* __restrict__ db0, const float* __restrict__ db1,
    const float* __restrict__ db2, const float* __restrict__ hv1f,
    const float* __restrict__ g2, const float* __restrict__ be2,
    float* __restrict__ out, int Nn) {
  __shared__ __align__(16) char lds[16384 + 32768 + 32768];
  char* A0 = lds;
  char* D0 = lds + 16384;
  char* D1 = lds + 16384 + 32768;
  float* Y = (float*)D0;
  const int tid = threadIdx.x, wid = tid >> 6, lane = tid & 63;
  const int l15 = lane & 15, lhi = lane >> 4;
  const int row0 = blockIdx.x * 64;

  // stage x (bf16 [64][128]) into A0, swizzled
#pragma unroll
  for (int p = 0; p < 4; ++p) {
    int idx = p * 256 + tid;
    int r = idx >> 4, c = idx & 15;
    uint4 v = make_uint4(0u, 0u, 0u, 0u);
    if (row0 + r < Nn) v = ((const uint4*)xb)[(size_t)(row0 + r) * 16 + c];
    *(uint4*)(A0 + r * 256 + ((c * 16) ^ ((r & 7) << 4))) = v;
  }
  __syncthreads();

  // GEMM0: d0 = gelu(x @ W0 + b0), K=128, wave owns 64 of 256 cols
  {
    f32x4 acc[4][4];
#pragma unroll
    for (int mt = 0; mt < 4; ++mt)
#pragma unroll
      for (int ct = 0; ct < 4; ++ct) acc[mt][ct] = 0.f;
#pragma unroll
    for (int ks = 0; ks < 4; ++ks) {
      bf16x8 a[4];
#pragma unroll
      for (int mt = 0; mt < 4; ++mt) {
        int row = mt * 16 + l15;
        a[mt] = *(bf16x8*)(A0 + row * 256 + ((ks * 64 + lhi * 16) ^ ((row & 7) << 4)));
      }
#pragma unroll
      for (int ct = 0; ct < 4; ++ct) {
        uint4 bv = ((const uint4*)pd0)[(size_t)(wid * 16 + ct * 4 + ks) * 64 + lane];
        bf16x8 b = *(bf16x8*)&bv;
#pragma unroll
        for (int mt = 0; mt < 4; ++mt)
          acc[mt][ct] = __builtin_amdgcn_mfma_f32_16x16x32_bf16(a[mt], b, acc[mt][ct], 0, 0, 0);
      }
    }
#pragma unroll
    for (int ct = 0; ct < 4; ++ct) {
      float bb = db0[wid * 64 + ct * 16 + l15];
      int col = wid * 64 + ct * 16 + l15;
#pragma unroll
      for (int mt = 0; mt < 4; ++mt)
#pragma unroll
        for (int j = 0; j < 4; ++j) {
          int r = mt * 16 + lhi * 4 + j;
          *(unsigned short*)(D0 + r * 512 + ((col * 2) ^ ((r & 7) << 4))) =
              f2bf(gelu_f(acc[mt][ct][j] + bb));
        }
    }
  }
  __syncthreads();

  // GEMM1: d1 = gelu(d0 @ W1 + b1), K=256
  {
    f32x4 acc[4][4];
#pragma unroll
    for (int mt = 0; mt < 4; ++mt)
#pragma unroll
      for (int ct = 0; ct < 4; ++ct) acc[mt][ct] = 0.f;
#pragma unroll
    for (int ks = 0; ks < 8; ++ks) {
      bf16x8 a[4];
#pragma unroll
      for (int mt = 0; mt < 4; ++mt) {
        int row = mt * 16 + l15;
        a[mt] = *(bf16x8*)(D0 + row * 512 + ((ks * 64 + lhi * 16) ^ ((row & 7) << 4)));
      }
#pragma unroll
      for (int ct = 0; ct < 4; ++ct) {
        uint4 bv = ((const uint4*)pd1)[(size_t)(wid * 32 + ct * 8 + ks) * 64 + lane];
        bf16x8 b = *(bf16x8*)&bv;
#pragma unroll
        for (int mt = 0; mt < 4; ++mt)
          acc[mt][ct] = __builtin_amdgcn_mfma_f32_16x16x32_bf16(a[mt], b, acc[mt][ct], 0, 0, 0);
      }
    }
#pragma unroll
    for (int ct = 0; ct < 4; ++ct) {
      float bb = db1[wid * 64 + ct * 16 + l15];
      int col = wid * 64 + ct * 16 + l15;
#pragma unroll
      for (int mt = 0; mt < 4; ++mt)
#pragma unroll
        for (int j = 0; j < 4; ++j) {
          int r = mt * 16 + lhi * 4 + j;
          *(unsigned short*)(D1 + r * 512 + ((col * 2) ^ ((r & 7) << 4))) =
              f2bf(gelu_f(acc[mt][ct][j] + bb));
        }
    }
  }
  __syncthreads();

  // GEMM2: y = d1 @ W2 + b2 + residual, K=256, N=128; write fp32 Y (overlays D0)
  {
    f32x4 acc[4][2];
#pragma unroll
    for (int mt = 0; mt < 4; ++mt)
#pragma unroll
      for (int ct = 0; ct < 2; ++ct) acc[mt][ct] = 0.f;
#pragma unroll
    for (int ks = 0; ks < 8; ++ks) {
      bf16x8 a[4];
#pragma unroll
      for (int mt = 0; mt < 4; ++mt) {
        int row = mt * 16 + l15;
        a[mt] = *(bf16x8*)(D1 + row * 512 + ((ks * 64 + lhi * 16) ^ ((row & 7) << 4)));
      }
#pragma unroll
      for (int ct = 0; ct < 2; ++ct) {
        uint4 bv = ((const uint4*)pd2)[(size_t)(wid * 16 + ct * 8 + ks) * 64 + lane];
        bf16x8 b = *(bf16x8*)&bv;
#pragma unroll
        for (int mt = 0; mt < 4; ++mt)
          acc[mt][ct] = __builtin_amdgcn_mfma_f32_16x16x32_bf16(a[mt], b, acc[mt][ct], 0, 0, 0);
      }
    }
    __syncthreads();  // D0 reads done everywhere (GEMM1 passed); safe to overlay Y
#pragma unroll
    for (int ct = 0; ct < 2; ++ct) {
      float bb = db2[wid * 32 + ct * 16 + l15];
      int col = wid * 32 + ct * 16 + l15;
#pragma unroll
      for (int mt = 0; mt < 4; ++mt)
#pragma unroll
        for (int j = 0; j < 4; ++j) {
          int r = mt * 16 + lhi * 4 + j;
          int grow = row0 + r;
          float res = (grow < Nn) ? hv1f[(size_t)grow * 128 + col] : 0.f;
          Y[r * 128 + col] = acc[mt][ct][j] + bb + res;
        }
    }
  }
  __syncthreads();

  // LN2 -> out
  float g2a = g2[lane * 2], g2b = g2[lane * 2 + 1];
  float ba = be2[lane * 2], bbx = be2[lane * 2 + 1];
  for (int ii = 0; ii < 16; ++ii) {
    int r = wid * 16 + ii;
    int grow = row0 + r;
    if (grow >= Nn) continue;  // wave-uniform
    float2 xy = *(float2*)&Y[r * 128 + lane * 2];
    float sum = xy.x + xy.y, sq = xy.x * xy.x + xy.y * xy.y;
#pragma unroll
    for (int off = 32; off > 0; off >>= 1) {
      sum += __shfl_xor(sum, off);
      sq += __shfl_xor(sq, off);
    }
    float mu = sum * (1.f / 128.f);
    float var = sq * (1.f / 128.f) - mu * mu;
    float rs = rsqrtf(var + 1e-5f);
    float y0 = (xy.x - mu) * rs * g2a + ba;
    float y1 = (xy.y - mu) * rs * g2b + bbx;
    *(float2*)&out[(size_t)grow * 128 + lane * 2] = make_float2(y0, y1);
  }
}

// ---------------- host ----------------
extern "C" void kernel_launch(void* const* d_in, const int* in_sizes, int n_in,
                              void* d_out, int out_size, void* d_ws, size_t ws_size,
                              hipStream_t stream) {
  const float* hV  = (const float*)d_in[0];
  const float* hE  = (const float*)d_in[1];
  const int* eidx  = (const int*)d_in[2];
  const float* mw0 = (const float*)d_in[3];
  const float* mb0 = (const float*)d_in[4];
  const float* mw1 = (const float*)d_in[5];
  const float* mb1 = (const float*)d_in[6];
  const float* dw0 = (const float*)d_in[7];
  const float* db0 = (const float*)d_in[8];
  const float* dw1 = (const float*)d_in[9];
  const float* db1 = (const float*)d_in[10];
  const float* dw2 = (const float*)d_in[11];
  const float* db2 = (const float*)d_in[12];
  const float* g1  = (const float*)d_in[13];
  const float* be1 = (const float*)d_in[14];
  const float* g2  = (const float*)d_in[15];
  const float* be2 = (const float*)d_in[16];
  const int Nn = in_sizes[0] / 128;
  const int E  = in_sizes[1] / 256;

  char* ws = (char*)d_ws;
  size_t off = 0;
  auto alloc = [&](size_t bytes) -> char* {
    off = (off + 255) & ~(size_t)255;
    char* p = ws + off;
    off += bytes;
    return p;
  };
  unsigned short* hmsg = (unsigned short*)alloc((size_t)E * 128 * 2);
  float* hv1f          = (float*)alloc((size_t)Nn * 128 * 4);
  unsigned short* hv1b = (unsigned short*)alloc((size_t)Nn * 128 * 2);
  unsigned short* pw0  = (unsigned short*)alloc(32768 * 2);
  unsigned short* pw1  = (unsigned short*)alloc(16384 * 2);
  unsigned short* pd0  = (unsigned short*)alloc(32768 * 2);
  unsigned short* pd1  = (unsigned short*)alloc(65536 * 2);
  unsigned short* pd2  = (unsigned short*)alloc(32768 * 2);
  int* counts    = (int*)alloc((size_t)Nn * 4);
  int* row_start = (int*)alloc((size_t)(Nn + 1) * 4);
  int* cursor    = (int*)alloc((size_t)Nn * 4);
  int* eorder    = (int*)alloc((size_t)E * 4);

  hipMemsetAsync(counts, 0, (size_t)Nn * 4, stream);
  k_pack<<<352, 64, 0, stream>>>(mw0, mw1, dw0, dw1, dw2, pw0, pw1, pd0, pd1, pd2);
  k_hist<<<(E + 255) / 256, 256, 0, stream>>>(eidx, counts, E);
  k_scan<<<1, 1024, 0, stream>>>(counts, row_start, cursor, Nn);
  k_scatter<<<(E + 255) / 256, 256, 0, stream>>>(eidx, cursor, eorder, E);
  k_edge<<<512, 256, 0, stream>>>(hE, pw0, pw1, mb0, mb1, hmsg, E);
  k_aggln<<<(Nn + 3) / 4, 256, 0, stream>>>((const unsigned*)hmsg, (const float2*)hV,
                                            row_start, eorder, g1, be1,
                                            (float2*)hv1f, (unsigned*)hv1b, Nn);
  const int nt = (Nn + 63) / 64;
  k_node<<<nt, 256, 0, stream>>>(hv1b, pd0, pd1, pd2, db0, db1, db2,
                                 hv1f, g2, be2, (float*)d_out, Nn);
}